// Round 1
// baseline (783.838 us; speedup 1.0000x reference)
//
#include <hip/hip_runtime.h>
#include <math.h>

#define B_ 16
#define L_ 4096
#define H_ 8
#define D_ 64
#define HD_ (H_*D_)     // 512
#define U_ 45
#define UP_ 48
#define NCHUNK 32
#define CHLEN 128       // L_/NCHUNK
#define NSPLIT 4
#define KSPAN 1024      // L_/NSPLIT
#define PITCH 65        // LDS pitch: odd -> <=2-way bank conflicts (free on CDNA4)

// ---------------- Phase A: sparsity measure M ----------------
// M[bh,q] = max_s(Q_q . K2_s) - (1/L) * sum_s(Q_q . K2_s), K2 = K[idx_s]^2
__global__ __launch_bounds__(256) void kM(const float* __restrict__ Q, const float* __restrict__ K,
                                          const int* __restrict__ idx, int S, float* __restrict__ M) {
    int blk = blockIdx.x;            // bh*(L/256) + chunk
    int chunk = blk & 15;            // L_/256 = 16
    int bh = blk >> 4;
    int b = bh >> 3, h = bh & 7;
    __shared__ float k2[45 * 64];
    for (int i = threadIdx.x; i < S * D_; i += 256) {
        int s = i >> 6, d = i & 63;
        float kv = K[(((size_t)b * L_ + idx[s]) * H_ + h) * D_ + d];
        k2[i] = kv * kv;
    }
    __syncthreads();
    int q = chunk * 256 + threadIdx.x;
    const float4* qp = (const float4*)(Q + (((size_t)b * L_ + q) * H_ + h) * D_);
    float4 qr[16];
#pragma unroll
    for (int c = 0; c < 16; c++) qr[c] = qp[c];
    float mx = -INFINITY, sm = 0.f;
    for (int s = 0; s < S; s++) {
        const float4* kp = (const float4*)(k2 + s * D_);   // uniform addr -> LDS broadcast
        float d0 = 0, d1 = 0, d2 = 0, d3 = 0;
#pragma unroll
        for (int c = 0; c < 16; c++) {
            float4 kv = kp[c];
            d0 += qr[c].x * kv.x; d1 += qr[c].y * kv.y;
            d2 += qr[c].z * kv.z; d3 += qr[c].w * kv.w;
        }
        float dot = (d0 + d1) + (d2 + d3);
        mx = fmaxf(mx, dot); sm += dot;
    }
    M[(size_t)bh * L_ + q] = mx - sm * (1.0f / (float)L_);
}

// ---------------- Phase B: top-45 per (b,h) ----------------
__global__ __launch_bounds__(256) void kTop(const float* __restrict__ M, int* __restrict__ mtop) {
    int bh = blockIdx.x;
    __shared__ float mv[L_];
    __shared__ float rv[256];
    __shared__ int   ri[256];
    for (int i = threadIdx.x; i < L_; i += 256) mv[i] = M[(size_t)bh * L_ + i];
    __syncthreads();
    for (int it = 0; it < U_; it++) {
        float bv = -INFINITY; int bi = 0x7fffffff;
        for (int i = threadIdx.x; i < L_; i += 256) {
            float v = mv[i];
            if (v > bv) { bv = v; bi = i; }  // ascending scan + strict > => lowest index on ties
        }
        rv[threadIdx.x] = bv; ri[threadIdx.x] = bi;
        __syncthreads();
        for (int off = 128; off > 0; off >>= 1) {
            if (threadIdx.x < off) {
                float v2 = rv[threadIdx.x + off]; int i2 = ri[threadIdx.x + off];
                if (v2 > rv[threadIdx.x] || (v2 == rv[threadIdx.x] && i2 < ri[threadIdx.x])) {
                    rv[threadIdx.x] = v2; ri[threadIdx.x] = i2;
                }
            }
            __syncthreads();
        }
        if (threadIdx.x == 0) { mtop[bh * U_ + it] = ri[0]; mv[ri[0]] = -INFINITY; }
        __syncthreads();
    }
}

// ---------------- Phase C: chunked cumsum of V -> out ----------------
__global__ __launch_bounds__(64) void kSum(const float* __restrict__ V, float* __restrict__ cs) {
    int blk = blockIdx.x;            // bh*NCHUNK + c
    int c = blk & 31, bh = blk >> 5;
    int b = bh >> 3, h = bh & 7;
    size_t base = (((size_t)b * L_ + c * CHLEN) * H_ + h) * D_ + threadIdx.x;
    float acc = 0.f;
#pragma unroll 8
    for (int i = 0; i < CHLEN; i++) acc += V[base + (size_t)i * HD_];
    cs[((size_t)bh * NCHUNK + c) * D_ + threadIdx.x] = acc;
}

__global__ __launch_bounds__(64) void kScan(float* __restrict__ cs) {
    int bh = blockIdx.x;
    int d = threadIdx.x;
    float run = 0.f;
    for (int c = 0; c < NCHUNK; c++) {
        size_t i = ((size_t)bh * NCHUNK + c) * D_ + d;
        float t = cs[i]; cs[i] = run; run += t;
    }
}

__global__ __launch_bounds__(64) void kCum(const float* __restrict__ V, const float* __restrict__ cs,
                                           float* __restrict__ out) {
    int blk = blockIdx.x;
    int c = blk & 31, bh = blk >> 5;
    int b = bh >> 3, h = bh & 7;
    size_t base = (((size_t)b * L_ + c * CHLEN) * H_ + h) * D_ + threadIdx.x;
    float acc = cs[((size_t)bh * NCHUNK + c) * D_ + threadIdx.x];
#pragma unroll 4
    for (int i = 0; i < CHLEN; i++) {
        acc += V[base + (size_t)i * HD_];
        out[base + (size_t)i * HD_] = acc;
    }
}

// ---------------- Phase D: flash attention over selected queries (split-K) ----------------
__global__ __launch_bounds__(128) void kFlash(const float* __restrict__ Q, const float* __restrict__ K,
                                              const float* __restrict__ V, const int* __restrict__ mtop,
                                              float* __restrict__ Opart, float* __restrict__ mpart,
                                              float* __restrict__ lpart) {
    int x = blockIdx.x;              // bh*NSPLIT + ks
    int ks = x & 3, bh = x >> 2;
    int b = bh >> 3, h = bh & 7;
    int ko = ks * KSPAN;
    int tid = threadIdx.x;
    int wave = tid >> 6, lane = tid & 63;

    __shared__ float Qs[UP_ * PITCH];
    __shared__ float Ks[64 * PITCH];
    __shared__ float Vs[64 * PITCH];
    __shared__ float Ps[UP_ * PITCH];
    __shared__ float mrun[UP_], lrun[UP_], alph[UP_];
    __shared__ int   mt[UP_];
    __shared__ int   kmaxs;

    if (tid < UP_) {
        int m = (tid < U_) ? mtop[bh * U_ + tid] : -1;
        mt[tid] = m; mrun[tid] = -INFINITY; lrun[tid] = 0.f;
    }
    __syncthreads();
    if (tid == 0) {
        int km = 0;
        for (int u2 = 0; u2 < U_; u2++) km = max(km, mt[u2] + 1);
        kmaxs = km;
    }
    // stage selected Q rows
    for (int i = tid; i < UP_ * 16; i += 128) {
        int u2 = i >> 4, cc = i & 15;
        float4 qv = make_float4(0.f, 0.f, 0.f, 0.f);
        if (u2 < U_) {
            const float4* qp = (const float4*)(Q + (((size_t)b * L_ + mt[u2]) * H_ + h) * D_);
            qv = qp[cc];
        }
        float* dst = Qs + u2 * PITCH + cc * 4;
        dst[0] = qv.x; dst[1] = qv.y; dst[2] = qv.z; dst[3] = qv.w;
    }
    __syncthreads();
    int kend = min(kmaxs, ko + KSPAN);

    float o[6][4];
#pragma unroll
    for (int a = 0; a < 6; a++)
#pragma unroll
        for (int bb = 0; bb < 4; bb++) o[a][bb] = 0.f;
    int dg = tid & 15, qw = tid >> 4;        // GEMM2/output mapping: 6q x 4d per thread
    int kg = lane & 15, qg = lane >> 4;      // GEMM1 mapping: 6q x 4k per lane
    int qbase = wave * 24 + qg * 6;

    for (int jt = ko; jt < kend; jt += 64) {
        // stage K,V tile (64 rows x 64)
        for (int i = tid; i < 64 * 16; i += 128) {
            int r = i >> 4, cc = i & 15;
            size_t gidx = (((size_t)b * L_ + jt + r) * H_ + h) * D_ + cc * 4;
            const float4 kv = *(const float4*)(K + gidx);
            const float4 vv = *(const float4*)(V + gidx);
            float* dk = Ks + r * PITCH + cc * 4;
            dk[0] = kv.x; dk[1] = kv.y; dk[2] = kv.z; dk[3] = kv.w;
            float* dv = Vs + r * PITCH + cc * 4;
            dv[0] = vv.x; dv[1] = vv.y; dv[2] = vv.z; dv[3] = vv.w;
        }
        __syncthreads();
        // GEMM1: S = Q K^T (6q x 4k per lane)
        float s[6][4];
#pragma unroll
        for (int a = 0; a < 6; a++)
#pragma unroll
            for (int bb = 0; bb < 4; bb++) s[a][bb] = 0.f;
#pragma unroll 8
        for (int d = 0; d < D_; d++) {
            float kv[4], qv[6];
#pragma unroll
            for (int kk = 0; kk < 4; kk++) kv[kk] = Ks[(kg * 4 + kk) * PITCH + d];
#pragma unroll
            for (int qq = 0; qq < 6; qq++) qv[qq] = Qs[(qbase + qq) * PITCH + d];
#pragma unroll
            for (int qq = 0; qq < 6; qq++)
#pragma unroll
                for (int kk = 0; kk < 4; kk++) s[qq][kk] += qv[qq] * kv[kk];
        }
#pragma unroll
        for (int qq = 0; qq < 6; qq++)
#pragma unroll
            for (int kk = 0; kk < 4; kk++)
                Ps[(qbase + qq) * PITCH + kg * 4 + kk] = s[qq][kk] * 0.125f;  // scale = 1/sqrt(64)
        __syncthreads();
        // online softmax: lanes 0..23 of each wave own one query row each
        if (lane < 24) {
            int q = wave * 24 + lane;
            int m = mt[q];
            float* prow = Ps + q * PITCH;
            if (q >= U_ || m < jt) {
                for (int j = 0; j < 64; j++) prow[j] = 0.f;
                alph[q] = 1.f;
            } else {
                int nv = m - jt + 1; if (nv > 64) nv = 64;
                float tmax = -INFINITY;
                for (int j = 0; j < nv; j++) tmax = fmaxf(tmax, prow[j]);
                float mo = mrun[q];
                float nm = fmaxf(mo, tmax);
                float al = __expf(mo - nm);    // mo=-inf -> 0
                float sum = 0.f;
                for (int j = 0; j < nv; j++) { float p = __expf(prow[j] - nm); prow[j] = p; sum += p; }
                for (int j = nv; j < 64; j++) prow[j] = 0.f;
                mrun[q] = nm; lrun[q] = lrun[q] * al + sum; alph[q] = al;
            }
        }
        __syncthreads();
        // GEMM2: O = alpha*O + P V (6q x 4d per thread)
        {
            float alq[6];
#pragma unroll
            for (int qq = 0; qq < 6; qq++) alq[qq] = alph[qw * 6 + qq];
#pragma unroll
            for (int qq = 0; qq < 6; qq++)
#pragma unroll
                for (int i2 = 0; i2 < 4; i2++) o[qq][i2] *= alq[qq];
#pragma unroll 8
            for (int j = 0; j < 64; j++) {
                float vv[4], pq[6];
#pragma unroll
                for (int i2 = 0; i2 < 4; i2++) vv[i2] = Vs[j * PITCH + dg * 4 + i2];
#pragma unroll
                for (int qq = 0; qq < 6; qq++) pq[qq] = Ps[(qw * 6 + qq) * PITCH + j];
#pragma unroll
                for (int qq = 0; qq < 6; qq++)
#pragma unroll
                    for (int i2 = 0; i2 < 4; i2++) o[qq][i2] += pq[qq] * vv[i2];
            }
        }
        __syncthreads();
    }
    // write split partials (unnormalized O, running m, running l)
#pragma unroll
    for (int qq = 0; qq < 6; qq++) {
        int q = qw * 6 + qq;
        float* dst = Opart + (((size_t)x * UP_) + q) * D_ + dg * 4;
#pragma unroll
        for (int i2 = 0; i2 < 4; i2++) dst[i2] = o[qq][i2];
    }
    if (tid < UP_) { mpart[(size_t)x * UP_ + tid] = mrun[tid]; lpart[(size_t)x * UP_ + tid] = lrun[tid]; }
}

// ---------------- Phase E: merge split-K partials, scatter into out ----------------
__global__ __launch_bounds__(256) void kMerge(const float* __restrict__ Opart, const float* __restrict__ mpart,
                                              const float* __restrict__ lpart, const int* __restrict__ mtop,
                                              float* __restrict__ out) {
    int bh = blockIdx.x; int b = bh >> 3, h = bh & 7;
    for (int idx = threadIdx.x; idx < U_ * D_; idx += 256) {
        int q = idx >> 6, d = idx & 63;
        float mvals[NSPLIT];
        float mmax = -INFINITY;
#pragma unroll
        for (int i = 0; i < NSPLIT; i++) {
            mvals[i] = mpart[(size_t)(bh * NSPLIT + i) * UP_ + q];
            mmax = fmaxf(mmax, mvals[i]);
        }
        float Lsum = 0.f, val = 0.f;
#pragma unroll
        for (int i = 0; i < NSPLIT; i++) {
            float w = __expf(mvals[i] - mmax);
            Lsum += lpart[(size_t)(bh * NSPLIT + i) * UP_ + q] * w;
            val  += Opart[((size_t)(bh * NSPLIT + i) * UP_ + q) * D_ + d] * w;
        }
        int m = mtop[bh * U_ + q];
        out[(((size_t)b * L_ + m) * H_ + h) * D_ + d] = val / Lsum;
    }
}

extern "C" void kernel_launch(void* const* d_in, const int* in_sizes, int n_in,
                              void* d_out, int out_size, void* d_ws, size_t ws_size,
                              hipStream_t stream) {
    const float* Q = (const float*)d_in[0];
    const float* K = (const float*)d_in[1];
    const float* V = (const float*)d_in[2];
    const int* idx = (const int*)d_in[3];
    int S = in_sizes[3]; if (S > 45) S = 45;
    float* out = (float*)d_out;
    float* ws = (float*)d_ws;

    // workspace layout (floats)
    float* M     = ws;                 // B*H*L          = 524288
    float* cs    = ws + 524288;        // B*H*32*64      = 262144
    float* Opart = ws + 786432;        // 512*48*64      = 1572864
    float* mpart = ws + 2359296;       // 512*48         = 24576
    float* lpart = ws + 2383872;       // 512*48         = 24576
    int*   mtop  = (int*)(ws + 2408448); // 128*45       = 5760  (total ~9.7 MB)

    kM   <<<B_ * H_ * (L_ / 256), 256, 0, stream>>>(Q, K, idx, S, M);
    kTop <<<B_ * H_,              256, 0, stream>>>(M, mtop);
    kSum <<<B_ * H_ * NCHUNK,      64, 0, stream>>>(V, cs);
    kScan<<<B_ * H_,               64, 0, stream>>>(cs);
    kCum <<<B_ * H_ * NCHUNK,      64, 0, stream>>>(V, cs, out);
    kFlash<<<B_ * H_ * NSPLIT,    128, 0, stream>>>(Q, K, V, mtop, Opart, mpart, lpart);
    kMerge<<<B_ * H_,             256, 0, stream>>>(Opart, mpart, lpart, mtop, out);
}

// Round 2
// 700.807 us; speedup vs baseline: 1.1185x; 1.1185x over previous
//
#include <hip/hip_runtime.h>
#include <math.h>

#define B_ 16
#define L_ 4096
#define H_ 8
#define D_ 64
#define HD_ (H_*D_)     // 512
#define U_ 45
#define UP_ 48
#define NCHUNK 32
#define CHLEN 128       // L_/NCHUNK
#define QP 68           // Qs bf16 pitch (conflict-free-ish, 8B aligned chunks)

__device__ inline float blo(unsigned int u) { return __uint_as_float(u << 16); }
__device__ inline float bhi(unsigned int u) { return __uint_as_float(u & 0xFFFF0000u); }
__device__ inline unsigned int pk2(float a, float b) {
    return (__float_as_uint(b) & 0xFFFF0000u) | (__float_as_uint(a) >> 16);
}

// ---------------- Phase A: sparsity measure M (fp32, unchanged — drives selection) ----------------
__global__ __launch_bounds__(256) void kM(const float* __restrict__ Q, const float* __restrict__ K,
                                          const int* __restrict__ idx, int S, float* __restrict__ M) {
    int blk = blockIdx.x;
    int chunk = blk & 15;
    int bh = blk >> 4;
    int b = bh >> 3, h = bh & 7;
    __shared__ float k2[45 * 64];
    for (int i = threadIdx.x; i < S * D_; i += 256) {
        int s = i >> 6, d = i & 63;
        float kv = K[(((size_t)b * L_ + idx[s]) * H_ + h) * D_ + d];
        k2[i] = kv * kv;
    }
    __syncthreads();
    int q = chunk * 256 + threadIdx.x;
    const float4* qp = (const float4*)(Q + (((size_t)b * L_ + q) * H_ + h) * D_);
    float4 qr[16];
#pragma unroll
    for (int c = 0; c < 16; c++) qr[c] = qp[c];
    float mx = -INFINITY, sm = 0.f;
    for (int s = 0; s < S; s++) {
        const float4* kp = (const float4*)(k2 + s * D_);
        float d0 = 0, d1 = 0, d2 = 0, d3 = 0;
#pragma unroll
        for (int c = 0; c < 16; c++) {
            float4 kv = kp[c];
            d0 += qr[c].x * kv.x; d1 += qr[c].y * kv.y;
            d2 += qr[c].z * kv.z; d3 += qr[c].w * kv.w;
        }
        float dot = (d0 + d1) + (d2 + d3);
        mx = fmaxf(mx, dot); sm += dot;
    }
    M[(size_t)bh * L_ + q] = mx - sm * (1.0f / (float)L_);
}

// ---------------- Phase B: top-45 per (b,h), register-resident iterative argmax ----------------
__global__ __launch_bounds__(256) void kTop(const float* __restrict__ M, int* __restrict__ mtop) {
    int bh = blockIdx.x, t = threadIdx.x;
    int lane = t & 63, wid = t >> 6;
    float mv[16];
#pragma unroll
    for (int w = 0; w < 16; w++) mv[w] = M[(size_t)bh * L_ + w * 256 + t];
    __shared__ float swv[4];
    __shared__ int swi[4];
    for (int it = 0; it < U_; it++) {
        float bv = -INFINITY; int bi = 1 << 30;
#pragma unroll
        for (int w = 0; w < 16; w++) {
            if (mv[w] > bv) { bv = mv[w]; bi = w * 256 + t; }
        }
#pragma unroll
        for (int off = 1; off < 64; off <<= 1) {
            float ov = __shfl_xor(bv, off); int oi = __shfl_xor(bi, off);
            if (ov > bv || (ov == bv && oi < bi)) { bv = ov; bi = oi; }
        }
        if (lane == 0) { swv[wid] = bv; swi[wid] = bi; }
        __syncthreads();
        float fv = swv[0]; int fi = swi[0];
        for (int w2 = 1; w2 < 4; w2++) {
            if (swv[w2] > fv || (swv[w2] == fv && swi[w2] < fi)) { fv = swv[w2]; fi = swi[w2]; }
        }
        if (t == 0) mtop[bh * U_ + it] = fi;
        int wr = fi >> 8;
        bool own = ((fi & 255) == t);
#pragma unroll
        for (int w = 0; w < 16; w++) mv[w] = (own && w == wr) ? -INFINITY : mv[w];
        __syncthreads();
    }
}

// ---------------- Phase C: chunked cumsum of V -> out ----------------
__global__ __launch_bounds__(64) void kSum(const float* __restrict__ V, float* __restrict__ cs) {
    int blk = blockIdx.x;
    int c = blk & 31, bh = blk >> 5;
    int b = bh >> 3, h = bh & 7;
    size_t base = (((size_t)b * L_ + c * CHLEN) * H_ + h) * D_ + threadIdx.x;
    float acc = 0.f;
#pragma unroll 8
    for (int i = 0; i < CHLEN; i++) acc += V[base + (size_t)i * HD_];
    cs[((size_t)bh * NCHUNK + c) * D_ + threadIdx.x] = acc;
}

__global__ __launch_bounds__(64) void kScan(float* __restrict__ cs) {
    int bh = blockIdx.x;
    int d = threadIdx.x;
    float run = 0.f;
    for (int c = 0; c < NCHUNK; c++) {
        size_t i = ((size_t)bh * NCHUNK + c) * D_ + d;
        float t = cs[i]; cs[i] = run; run += t;
    }
}

__global__ __launch_bounds__(64) void kCum(const float* __restrict__ V, const float* __restrict__ cs,
                                           float* __restrict__ out) {
    int blk = blockIdx.x;
    int c = blk & 31, bh = blk >> 5;
    int b = bh >> 3, h = bh & 7;
    size_t base = (((size_t)b * L_ + c * CHLEN) * H_ + h) * D_ + threadIdx.x;
    float acc = cs[((size_t)bh * NCHUNK + c) * D_ + threadIdx.x];
#pragma unroll 4
    for (int i = 0; i < CHLEN; i++) {
        acc += V[base + (size_t)i * HD_];
        out[base + (size_t)i * HD_] = acc;
    }
}

// ---------------- Phase D: per-wave-independent split-K flash attention ----------------
// Block = 128 thr (2 waves). Each wave owns k-range [ (ks*2+wave)*wkspan, +wkspan ), its own
// bf16 LDS K/V tile, zero in-loop barriers. Per lane: 6q x 8k scores, 6q x 8d output.
// K tile stored d-major with XOR swizzle on 16B k-groups: elem (d,k) at
//   d*64 + (((k>>3) ^ ((d>>2)&7))<<3) + (k&7)   -> b128 reads conflict-free.
__global__ __launch_bounds__(128, 2) void kFlash(const float* __restrict__ Q, const float* __restrict__ K,
                                                 const float* __restrict__ V, const int* __restrict__ mtop,
                                                 float* __restrict__ Opart, float* __restrict__ mpart,
                                                 float* __restrict__ lpart, int nsb, int wkspan) {
    int blk = blockIdx.x;
    int ks = blk % nsb;
    int bh = blk / nsb;
    int b = bh >> 3, h = bh & 7;
    int tid = threadIdx.x, wave = tid >> 6, lane = tid & 63;
    int qg = lane >> 3, kg = lane & 7;
    int qg6 = qg * 6;

    __shared__ unsigned short KsT[2][64 * 64];
    __shared__ unsigned short Vs[2][64 * 64];
    __shared__ unsigned short Qs[UP_ * QP];
    __shared__ int mt[UP_];
    __shared__ int kmaxs;

    if (tid < UP_) mt[tid] = (tid < U_) ? mtop[bh * U_ + tid] : -1;
    __syncthreads();
    if (tid == 0) {
        int km = 0;
        for (int u = 0; u < U_; u++) km = max(km, mt[u] + 1);
        kmaxs = km;
    }
    // stage selected Q rows (pre-scaled by 1/sqrt(D) = 0.125 — exact power of 2)
    for (int i = tid; i < UP_ * 16; i += 128) {
        int q = i >> 4, cc = i & 15;
        int r = mt[q] < 0 ? 0 : mt[q];
        const float4 qv = *(const float4*)(Q + (((size_t)b * L_ + r) * H_ + h) * D_ + cc * 4);
        *(uint2*)(Qs + q * QP + cc * 4) =
            make_uint2(pk2(qv.x * 0.125f, qv.y * 0.125f), pk2(qv.z * 0.125f, qv.w * 0.125f));
    }
    __syncthreads();

    int mtr[6];
#pragma unroll
    for (int qq = 0; qq < 6; qq++) mtr[qq] = mt[qg6 + qq];

    float o[6][8];
#pragma unroll
    for (int qq = 0; qq < 6; qq++)
#pragma unroll
        for (int dd = 0; dd < 8; dd++) o[qq][dd] = 0.f;
    float mrow[6], lrow[6];
#pragma unroll
    for (int qq = 0; qq < 6; qq++) { mrow[qq] = -INFINITY; lrow[qq] = 0.f; }

    int ko = (ks * 2 + wave) * wkspan;
    int kend = min(kmaxs, ko + wkspan);

    for (int jt = ko; jt < kend; jt += 64) {
        // ---- stage K (transposed+swizzled) and V (row-major) as bf16, this wave only ----
        for (int i = lane; i < 64 * 16; i += 64) {
            int r = i >> 4, cc = i & 15;
            size_t g = (((size_t)b * L_ + jt + r) * H_ + h) * D_ + cc * 4;
            const float4 kv = *(const float4*)(K + g);
            const float4 vv = *(const float4*)(V + g);
            *(uint2*)(Vs[wave] + r * 64 + cc * 4) = make_uint2(pk2(vv.x, vv.y), pk2(vv.z, vv.w));
            int g8 = r >> 3, kk = r & 7;
            int sw = (cc & 7);
            float kx[4] = { kv.x, kv.y, kv.z, kv.w };
#pragma unroll
            for (int t2 = 0; t2 < 4; t2++) {
                int d = cc * 4 + t2;
                KsT[wave][d * 64 + (((g8 ^ sw) << 3) | kk)] =
                    (unsigned short)(__float_as_uint(kx[t2]) >> 16);
            }
        }
        // ---- GEMM1: s[6q][8k] = Q . K^T (wave-local, waitcnt ordering only) ----
        float s[6][8];
#pragma unroll
        for (int qq = 0; qq < 6; qq++)
#pragma unroll
            for (int kk = 0; kk < 8; kk++) s[qq][kk] = 0.f;
        for (int ch = 0; ch < 16; ch++) {
            float qv[6][4];
#pragma unroll
            for (int qq = 0; qq < 6; qq++) {
                const uint2 u = *(const uint2*)(Qs + (qg6 + qq) * QP + ch * 4);
                qv[qq][0] = blo(u.x); qv[qq][1] = bhi(u.x);
                qv[qq][2] = blo(u.y); qv[qq][3] = bhi(u.y);
            }
            const int koff = (kg ^ (ch & 7)) << 3;
#pragma unroll
            for (int dd = 0; dd < 4; dd++) {
                const uint4 u = *(const uint4*)(KsT[wave] + (ch * 4 + dd) * 64 + koff);
                float kv[8] = { blo(u.x), bhi(u.x), blo(u.y), bhi(u.y),
                                blo(u.z), bhi(u.z), blo(u.w), bhi(u.w) };
#pragma unroll
                for (int qq = 0; qq < 6; qq++)
#pragma unroll
                    for (int kk = 0; kk < 8; kk++)
                        s[qq][kk] = fmaf(qv[qq][dd], kv[kk], s[qq][kk]);
            }
        }
        // ---- in-register online softmax (reduce across the 8 kg-lanes) ----
        int colb = jt + kg * 8;
        float al[6];
#pragma unroll
        for (int qq = 0; qq < 6; qq++) {
            float tm = -INFINITY;
#pragma unroll
            for (int kk = 0; kk < 8; kk++)
                if (colb + kk <= mtr[qq]) tm = fmaxf(tm, s[qq][kk]);
            tm = fmaxf(tm, __shfl_xor(tm, 1));
            tm = fmaxf(tm, __shfl_xor(tm, 2));
            tm = fmaxf(tm, __shfl_xor(tm, 4));
            float nm = fmaxf(mrow[qq], tm);
            float a = (nm == -INFINITY) ? 1.f : __expf(mrow[qq] - nm);
            mrow[qq] = nm;
            float rs = 0.f;
#pragma unroll
            for (int kk = 0; kk < 8; kk++) {
                float p = (colb + kk <= mtr[qq]) ? __expf(s[qq][kk] - nm) : 0.f;
                s[qq][kk] = p; rs += p;
            }
            rs += __shfl_xor(rs, 1);
            rs += __shfl_xor(rs, 2);
            rs += __shfl_xor(rs, 4);
            lrow[qq] = lrow[qq] * a + rs;
            al[qq] = a;
        }
#pragma unroll
        for (int qq = 0; qq < 6; qq++)
#pragma unroll
            for (int dd = 0; dd < 8; dd++) o[qq][dd] *= al[qq];
        // pack P pairs as bf16 for bpermute broadcast
        unsigned int ps[3][8];
#pragma unroll
        for (int pp = 0; pp < 3; pp++)
#pragma unroll
            for (int kk = 0; kk < 8; kk++) ps[pp][kk] = pk2(s[2 * pp][kk], s[2 * pp + 1][kk]);
        // ---- GEMM2: o[6q][8d] += P . V, P via ds_bpermute ----
        for (int jg = 0; jg < 8; jg++) {
            const int srcaddr = ((lane & 56) | jg) << 2;
#pragma unroll
            for (int jj = 0; jj < 8; jj++) {
                const int j = jg * 8 + jj;
                int p01 = __builtin_amdgcn_ds_bpermute(srcaddr, (int)ps[0][jj]);
                int p23 = __builtin_amdgcn_ds_bpermute(srcaddr, (int)ps[1][jj]);
                int p45 = __builtin_amdgcn_ds_bpermute(srcaddr, (int)ps[2][jj]);
                const uint4 u = *(const uint4*)(Vs[wave] + j * 64 + kg * 8);
                float vv[8] = { blo(u.x), bhi(u.x), blo(u.y), bhi(u.y),
                                blo(u.z), bhi(u.z), blo(u.w), bhi(u.w) };
                float pq[6] = { blo((unsigned)p01), bhi((unsigned)p01),
                                blo((unsigned)p23), bhi((unsigned)p23),
                                blo((unsigned)p45), bhi((unsigned)p45) };
#pragma unroll
                for (int qq = 0; qq < 6; qq++)
#pragma unroll
                    for (int dd = 0; dd < 8; dd++)
                        o[qq][dd] = fmaf(pq[qq], vv[dd], o[qq][dd]);
            }
        }
    }
    // ---- write per-wave split partials ----
    int nse = nsb * 2;
    int e = ks * 2 + wave;
    float* ob = Opart + ((size_t)(bh * nse + e)) * UP_ * D_;
#pragma unroll
    for (int qq = 0; qq < 6; qq++) {
        int q = qg6 + qq;
        *(float4*)(ob + q * D_ + kg * 8) = make_float4(o[qq][0], o[qq][1], o[qq][2], o[qq][3]);
        *(float4*)(ob + q * D_ + kg * 8 + 4) = make_float4(o[qq][4], o[qq][5], o[qq][6], o[qq][7]);
    }
    if (kg == 0) {
#pragma unroll
        for (int qq = 0; qq < 6; qq++) {
            mpart[(size_t)(bh * nse + e) * UP_ + qg6 + qq] = mrow[qq];
            lpart[(size_t)(bh * nse + e) * UP_ + qg6 + qq] = lrow[qq];
        }
    }
}

// ---------------- Phase E: merge split partials, scatter into out ----------------
__global__ __launch_bounds__(256) void kMerge(const float* __restrict__ Opart, const float* __restrict__ mpart,
                                              const float* __restrict__ lpart, const int* __restrict__ mtop,
                                              float* __restrict__ out, int nse) {
    int bh = blockIdx.x; int b = bh >> 3, h = bh & 7;
    for (int idx = threadIdx.x; idx < U_ * D_; idx += 256) {
        int q = idx >> 6, d = idx & 63;
        float mmax = -INFINITY;
        for (int i = 0; i < nse; i++) mmax = fmaxf(mmax, mpart[(size_t)(bh * nse + i) * UP_ + q]);
        float Ls = 0.f, val = 0.f;
        for (int i = 0; i < nse; i++) {
            float w = __expf(mpart[(size_t)(bh * nse + i) * UP_ + q] - mmax);
            Ls += lpart[(size_t)(bh * nse + i) * UP_ + q] * w;
            val += Opart[((size_t)(bh * nse + i) * UP_ + q) * D_ + d] * w;
        }
        int m = mtop[bh * U_ + q];
        out[(((size_t)b * L_ + m) * H_ + h) * D_ + d] = val / Ls;
    }
}

extern "C" void kernel_launch(void* const* d_in, const int* in_sizes, int n_in,
                              void* d_out, int out_size, void* d_ws, size_t ws_size,
                              hipStream_t stream) {
    const float* Q = (const float*)d_in[0];
    const float* K = (const float*)d_in[1];
    const float* V = (const float*)d_in[2];
    const int* idx = (const int*)d_in[3];
    int S = in_sizes[3]; if (S > 45) S = 45;
    float* out = (float*)d_out;
    float* ws = (float*)d_ws;

    // Adaptive split count: 2*nsb effective splits; Opart = 128*2*nsb*48*64 floats.
    size_t wsf = ws_size / 4;
    int nsb = 8;
    while (nsb > 1) {
        size_t opart = (size_t)128 * (2 * nsb) * UP_ * D_;
        size_t need = 5760 + opart + 2 * (size_t)128 * (2 * nsb) * UP_;
        size_t needAB = 5760 + 524288 + 262144;   // M + cs phase
        if (need <= wsf && needAB <= wsf) break;
        nsb >>= 1;
    }
    int nse = 2 * nsb;

    // layout: [mtop][ region shared by {M,cs} (phases A-C) and {Opart,mpart,lpart} (phases D-E) ]
    int* mtop = (int*)ws;
    float* rest = ws + 5760;
    float* M = rest;
    float* cs = rest + 524288;
    float* Opart = rest;
    float* mpart = Opart + (size_t)128 * nse * UP_ * D_;
    float* lpart = mpart + (size_t)128 * nse * UP_;

    kM   <<<B_ * H_ * (L_ / 256), 256, 0, stream>>>(Q, K, idx, S, M);
    kTop <<<B_ * H_,              256, 0, stream>>>(M, mtop);
    kSum <<<B_ * H_ * NCHUNK,      64, 0, stream>>>(V, cs);
    kScan<<<B_ * H_,               64, 0, stream>>>(cs);
    kCum <<<B_ * H_ * NCHUNK,      64, 0, stream>>>(V, cs, out);
    kFlash<<<B_ * H_ * nsb,       128, 0, stream>>>(Q, K, V, mtop, Opart, mpart, lpart, nsb, L_ / nse);
    kMerge<<<B_ * H_,             256, 0, stream>>>(Opart, mpart, lpart, mtop, out, nse);
}